// Round 1
// 651.100 us; speedup vs baseline: 1.0986x; 1.0986x over previous
//
#include <hip/hip_runtime.h>
#include <stdint.h>
#include <stddef.h>

// C[4096,11008] = X[4096,4096] @ W^T, W = int4 group-128 dequant.
// R4: counters (MfmaUtil 36, VALU 29, conflicts 0, HBM 18%) => schedule-bound
// at the 2-barrier 128x128 structure's documented ~900TF ceiling, with in-loop
// VALU dequant competing for issue. This round:
//  (1) W fully dequantized to f16 by a prepass (memory-bound ~25us); GEMM
//      K-loop has ZERO dequant VALU and ZERO ds_writes.
//  (2) GEMM re-structured to the verified 256x256/BK=64/8-wave 8-phase
//      counted-vmcnt schedule (T2+T3+T4+T5): 128KiB double-buffered LDS,
//      per phase {ds_read frags | stage one 16KB half via global_load_lds |
//      vmcnt(4) at MH=1 phases | s_barrier | setprio(1) 16xMFMA setprio(0) |
//      s_barrier}. vmcnt never drains to 0 in the loop: a half staged at
//      phase p is first read at p+4, retired by the vmcnt(4) at p+2/p+3.
//  (3) LDS: per-operand per-buffer two 16KB K-half sections; slot
//      su = kc2 ^ (row&3); staging pre-swizzles the GLOBAL address so the
//      gload_lds destination stays linear (both-sides-or-neither).

#define M_TOK 4096
#define K_IN  4096
#define N_OUT 11008
#define NGRP  32

#define MTI 16            // 4096/256
#define NTI 43            // 11008/256
#define TILES (MTI * NTI) // 688 = 8*86

#define BH_OFF ((size_t)M_TOK * K_IN * 2)   // Ah: 32 MiB, then Bh: 86 MiB

typedef _Float16 h8v __attribute__((ext_vector_type(8)));
typedef float    f4v __attribute__((ext_vector_type(4)));

__device__ __forceinline__ void gload16(const void* g, void* l) {
  __builtin_amdgcn_global_load_lds(
      (__attribute__((address_space(1))) void*)(g),
      (__attribute__((address_space(3))) void*)(l),
      16, 0, 0);
}

#define MEMFENCE asm volatile("" ::: "memory")
__device__ __forceinline__ void bar() {
  MEMFENCE;
  __builtin_amdgcn_s_barrier();
  MEMFENCE;
}
#define WAIT_VM4 asm volatile("s_waitcnt vmcnt(4)" ::: "memory")

// ---- prepass 1: X f32 -> f16, natural order ----
__global__ __launch_bounds__(256) void cvt_x_kernel(const float* __restrict__ x,
                                                    _Float16* __restrict__ xh) {
  size_t t = (size_t)blockIdx.x * 256 + threadIdx.x;
  const float4* s = (const float4*)x + t * 2;
  float4 a = s[0], b = s[1];
  h8v o;
  o[0] = (_Float16)a.x; o[1] = (_Float16)a.y; o[2] = (_Float16)a.z; o[3] = (_Float16)a.w;
  o[4] = (_Float16)b.x; o[5] = (_Float16)b.y; o[6] = (_Float16)b.z; o[7] = (_Float16)b.w;
  ((h8v*)xh)[t] = o;
}

// ---- prepass 2: full dequant W -> f16 [OUT][IN], natural order ----
// w[k=2i]   = (sext4(lo(b_i)) - z) * s = s*(lo^8) + c,  c = -s*(8+z)
__global__ __launch_bounds__(256) void dequant_w_kernel(const int* __restrict__ wp,
                                                        const float* __restrict__ ws,
                                                        const int* __restrict__ wz,
                                                        _Float16* __restrict__ bh) {
  size_t tg = (size_t)blockIdx.x * 256 + threadIdx.x;
  int j   = (int)(tg & 127);   // 128 threads per row, 16 ints each
  int row = (int)(tg >> 7);
  int g = j >> 2;              // 32 weights per thread, group = 128
  float s = ws[(size_t)row * NGRP + g];
  float c = -s * (8.0f + (float)wz[(size_t)row * NGRP + g]);
  const int4* src = (const int4*)(wp + (size_t)row * 2048 + j * 16);
  _Float16* dst = bh + (size_t)row * 4096 + j * 32;
#pragma unroll
  for (int b = 0; b < 4; ++b) {
    int4 v = src[b];
    int q[4] = {v.x, v.y, v.z, v.w};
    h8v o;
#pragma unroll
    for (int i = 0; i < 4; ++i) {
      int lo = (q[i] & 15) ^ 8;
      int hi = ((q[i] >> 4) & 15) ^ 8;
      o[2 * i]     = (_Float16)(s * (float)lo + c);
      o[2 * i + 1] = (_Float16)(s * (float)hi + c);
    }
    ((h8v*)dst)[b] = o;
  }
}

// ---- GEMM: 256x256 tile, BK=64, 8 waves (2M x 4N), 8-phase counted-vmcnt ----
// LDS per buffer: A 32KB (2 K-half sections of 16KB) + B 32KB. 2 buffers = 128KB.
// byte(row,kchunk) = sec(kchunk>>2)*16384 + (row*4 + ((kchunk&3)^(row&3)))*16
__global__ __launch_bounds__(512, 2) void gemm_kernel(
    const _Float16* __restrict__ Ah,
    const _Float16* __restrict__ Bh,
    float* __restrict__ C) {
  __shared__ __align__(128) char smem[131072];

  const int bid = blockIdx.x;
  // XCD swizzle, bijective (688 = 8*86): each XCD owns 2 full m-rows of tiles
  const int swz = (bid & 7) * 86 + (bid >> 3);
  const int mt = swz / NTI;
  const int nt = swz - mt * NTI;
  const int m0 = mt * 256;
  const int n0 = nt * 256;

  const int tid  = threadIdx.x;
  const int lane = tid & 63;
  const int wid  = tid >> 6;
  const int wm   = wid >> 2;   // 0..1
  const int wn   = wid & 3;    // 0..3
  const int lrow = lane & 15;
  const int quad = lane >> 4;

  // staging: thread covers rows r0, r0+16 of the tile, one 16B kchunk each.
  // pre-swizzled global kchunk so linear gload_lds dest realizes the LDS swizzle.
  const int r0  = wid * 32 + (lane >> 2);            // 0..255 (j=0), +16 (j=1)
  const int kc2 = (lane & 3) ^ ((lane >> 2) & 3);    // row&3 == (lane>>2)&3
  const size_t gA0 = (size_t)(m0 + r0) * K_IN + kc2 * 8;
  const size_t gB0 = (size_t)(n0 + r0) * K_IN + kc2 * 8;
  const int ldsl = wid * 2048;                       // + j*1024, wave-uniform

  // fragment read offsets (within a section)
  const int su   = quad ^ (lrow & 3);
  const int aoff = ((wm * 128 + lrow) * 4 + su) * 16;
  const int boff = 32768 + ((wn * 64 + lrow) * 4 + su) * 16;

  f4v acc[8][4];
#pragma unroll
  for (int i = 0; i < 8; ++i)
#pragma unroll
    for (int j = 0; j < 4; ++j) acc[i][j] = (f4v){0.f, 0.f, 0.f, 0.f};

#define STAGE_A(NXT, KT, KH)                                                   \
  { const _Float16* g_ = Ah + gA0 + (size_t)(KT) * 64 + (KH) * 32;             \
    char* l_ = smem + (NXT) * 65536 + (KH) * 16384 + ldsl;                     \
    gload16(g_, l_);                                                           \
    gload16(g_ + 16 * K_IN, l_ + 1024); }

#define STAGE_B(NXT, KT, KH)                                                   \
  { const _Float16* g_ = Bh + gB0 + (size_t)(KT) * 64 + (KH) * 32;             \
    char* l_ = smem + (NXT) * 65536 + 32768 + (KH) * 16384 + ldsl;             \
    gload16(g_, l_);                                                           \
    gload16(g_ + 16 * K_IN, l_ + 1024); }

  h8v af[4], bf[4];

// one phase: ds_read subtile, stage one half of a future tile, counted vmcnt,
// barrier, prioritized MFMA cluster, barrier.
#define PHASE(CUR, KS, MH, DO_STAGE, DO_VM)                                    \
  {                                                                            \
    const char* sec_ = smem + (CUR) * 65536 + (KS) * 16384;                    \
    if ((MH) == 0) {                                                           \
      _Pragma("unroll")                                                        \
      for (int nf = 0; nf < 4; ++nf)                                           \
        bf[nf] = *(const h8v*)(sec_ + boff + nf * 1024);                       \
    }                                                                          \
    _Pragma("unroll")                                                          \
    for (int i = 0; i < 4; ++i)                                                \
      af[i] = *(const h8v*)(sec_ + aoff + (MH) * 4096 + i * 1024);             \
    DO_STAGE;                                                                  \
    if (DO_VM) { WAIT_VM4; }                                                   \
    bar();                                                                     \
    __builtin_amdgcn_s_setprio(1);                                             \
    _Pragma("unroll")                                                          \
    for (int mi = 0; mi < 4; ++mi)                                             \
      _Pragma("unroll")                                                        \
      for (int nf = 0; nf < 4; ++nf)                                           \
        acc[(MH) * 4 + mi][nf] = __builtin_amdgcn_mfma_f32_16x16x32_f16(       \
            af[mi], bf[nf], acc[(MH) * 4 + mi][nf], 0, 0, 0);                  \
    __builtin_amdgcn_s_setprio(0);                                             \
    bar();                                                                     \
  }

  // prologue: tile 0 -> buf0 (A0,B0,A1,B1); retire A0,B0; leave A1,B1 in flight
  STAGE_A(0, 0, 0);
  STAGE_B(0, 0, 0);
  STAGE_A(0, 0, 1);
  STAGE_B(0, 0, 1);
  WAIT_VM4;
  bar();

  for (int t = 0; t < 64; t += 2) {
    const int t1 = t + 1;
    const int t2 = (t + 2 < 64) ? t + 2 : 63;  // tail: dummy restage, dead region
    // tile t from buf0, staging tile t+1 -> buf1
    PHASE(0, 0, 0, STAGE_A(1, t1, 0), 0)
    PHASE(0, 0, 1, STAGE_B(1, t1, 0), 1)
    PHASE(0, 1, 0, STAGE_A(1, t1, 1), 0)
    PHASE(0, 1, 1, STAGE_B(1, t1, 1), 1)
    // tile t+1 from buf1, staging tile t+2 -> buf0
    PHASE(1, 0, 0, STAGE_A(0, t2, 0), 0)
    PHASE(1, 0, 1, STAGE_B(0, t2, 0), 1)
    PHASE(1, 1, 0, STAGE_A(0, t2, 1), 0)
    PHASE(1, 1, 1, STAGE_B(0, t2, 1), 1)
  }

  // epilogue: C/D layout col = lane&15 (n), row = quad*4 + reg (m)
#pragma unroll
  for (int mf = 0; mf < 8; ++mf) {
#pragma unroll
    for (int rr = 0; rr < 4; ++rr) {
      int m = m0 + wm * 128 + mf * 16 + quad * 4 + rr;
      float* crow = C + (size_t)m * N_OUT + n0 + wn * 64 + lrow;
#pragma unroll
      for (int nf = 0; nf < 4; ++nf) crow[nf * 16] = acc[mf][nf][rr];
    }
  }
#undef PHASE
#undef STAGE_A
#undef STAGE_B
}

extern "C" void kernel_launch(void* const* d_in, const int* in_sizes, int n_in,
                              void* d_out, int out_size, void* d_ws, size_t ws_size,
                              hipStream_t stream) {
  const float* x   = (const float*)d_in[0];
  const int*   wp  = (const int*)d_in[1];
  const float* wsc = (const float*)d_in[2];
  const int*   wz  = (const int*)d_in[3];

  _Float16* Ah = (_Float16*)d_ws;
  _Float16* Bh = (_Float16*)((char*)d_ws + BH_OFF);

  cvt_x_kernel<<<(M_TOK * (size_t)K_IN) / (8 * 256), 256, 0, stream>>>(x, Ah);
  dequant_w_kernel<<<((size_t)N_OUT * 128) / 256, 256, 0, stream>>>(wp, wsc, wz, Bh);
  gemm_kernel<<<TILES, 512, 0, stream>>>(Ah, Bh, (float*)d_out);
}

// Round 2
// 638.238 us; speedup vs baseline: 1.1208x; 1.0202x over previous
//
#include <hip/hip_runtime.h>
#include <stdint.h>
#include <stddef.h>

// C[4096,11008] = X[4096,4096] @ W^T, W = int4 group-128 dequant.
// R5: R4's 8-phase 256x256 schedule landed (400us, VALU 29->14.5) but the LDS
// slot swizzle was wrong-axis: slot = kc ^ (row&3) leaves unit%8 covering only
// 4/8 chunk positions per 16-lane quad -> measured 4.0 extra cyc/ds_read_b128
// (SQ_LDS_BANK_CONFLICT 3.38e7 / 8.45M reads), ~16% of CU cycles.
// Fix: slot = kc ^ ((row>>1)&3). Over 16 consecutive rows unit%8 =
// 4*(row&1) + (q ^ ((row>>1)&3)) hits all 8 positions x2 lanes -> 2-way = free.
// Both-sides-or-neither: staging pre-swizzles the GLOBAL kchunk
// (kc = (lane&3) ^ ((lane>>3)&3), since dest-unit row bits [2:1] = lane [4:3]);
// reads use su = quad ^ ((lrow>>1)&3) (row bits [2:1] = lrow [2:1] everywhere).

#define M_TOK 4096
#define K_IN  4096
#define N_OUT 11008
#define NGRP  32

#define MTI 16            // 4096/256
#define NTI 43            // 11008/256
#define TILES (MTI * NTI) // 688 = 8*86

#define BH_OFF ((size_t)M_TOK * K_IN * 2)   // Ah: 32 MiB, then Bh: 86 MiB

typedef _Float16 h8v __attribute__((ext_vector_type(8)));
typedef float    f4v __attribute__((ext_vector_type(4)));

__device__ __forceinline__ void gload16(const void* g, void* l) {
  __builtin_amdgcn_global_load_lds(
      (__attribute__((address_space(1))) void*)(g),
      (__attribute__((address_space(3))) void*)(l),
      16, 0, 0);
}

#define MEMFENCE asm volatile("" ::: "memory")
__device__ __forceinline__ void bar() {
  MEMFENCE;
  __builtin_amdgcn_s_barrier();
  MEMFENCE;
}
#define WAIT_VM4 asm volatile("s_waitcnt vmcnt(4)" ::: "memory")

// ---- prepass 1: X f32 -> f16, natural order ----
__global__ __launch_bounds__(256) void cvt_x_kernel(const float* __restrict__ x,
                                                    _Float16* __restrict__ xh) {
  size_t t = (size_t)blockIdx.x * 256 + threadIdx.x;
  const float4* s = (const float4*)x + t * 2;
  float4 a = s[0], b = s[1];
  h8v o;
  o[0] = (_Float16)a.x; o[1] = (_Float16)a.y; o[2] = (_Float16)a.z; o[3] = (_Float16)a.w;
  o[4] = (_Float16)b.x; o[5] = (_Float16)b.y; o[6] = (_Float16)b.z; o[7] = (_Float16)b.w;
  ((h8v*)xh)[t] = o;
}

// ---- prepass 2: full dequant W -> f16 [OUT][IN], natural order ----
// w[k=2i] = (sext4(lo) - z) * s = s*(lo^8) + c,  c = -s*(8+z)
__global__ __launch_bounds__(256) void dequant_w_kernel(const int* __restrict__ wp,
                                                        const float* __restrict__ ws,
                                                        const int* __restrict__ wz,
                                                        _Float16* __restrict__ bh) {
  size_t tg = (size_t)blockIdx.x * 256 + threadIdx.x;
  int j   = (int)(tg & 127);   // 128 threads per row, 16 ints each
  int row = (int)(tg >> 7);
  int g = j >> 2;              // 32 weights per thread, group = 128
  float s = ws[(size_t)row * NGRP + g];
  float c = -s * (8.0f + (float)wz[(size_t)row * NGRP + g]);
  const int4* src = (const int4*)(wp + (size_t)row * 2048 + j * 16);
  _Float16* dst = bh + (size_t)row * 4096 + j * 32;
#pragma unroll
  for (int b = 0; b < 4; ++b) {
    int4 v = src[b];
    int q[4] = {v.x, v.y, v.z, v.w};
    h8v o;
#pragma unroll
    for (int i = 0; i < 4; ++i) {
      int lo = (q[i] & 15) ^ 8;
      int hi = ((q[i] >> 4) & 15) ^ 8;
      o[2 * i]     = (_Float16)(s * (float)lo + c);
      o[2 * i + 1] = (_Float16)(s * (float)hi + c);
    }
    ((h8v*)dst)[b] = o;
  }
}

// ---- GEMM: 256x256 tile, BK=64, 8 waves (2M x 4N), 8-phase counted-vmcnt ----
// LDS per buffer: A 32KB (2 K-half sections of 16KB) + B 32KB. 2 buffers = 128KB.
// byte(row,kchunk) = sec(kchunk>>2)*16384 + (row*4 + (kchunk&3)^((row>>1)&3))*16
__global__ __launch_bounds__(512, 2) void gemm_kernel(
    const _Float16* __restrict__ Ah,
    const _Float16* __restrict__ Bh,
    float* __restrict__ C) {
  __shared__ __align__(128) char smem[131072];

  const int bid = blockIdx.x;
  // XCD swizzle, bijective (688 = 8*86): each XCD owns 2 full m-rows of tiles
  const int swz = (bid & 7) * 86 + (bid >> 3);
  const int mt = swz / NTI;
  const int nt = swz - mt * NTI;
  const int m0 = mt * 256;
  const int n0 = nt * 256;

  const int tid  = threadIdx.x;
  const int lane = tid & 63;
  const int wid  = tid >> 6;
  const int wm   = wid >> 2;   // 0..1
  const int wn   = wid & 3;    // 0..3
  const int lrow = lane & 15;
  const int quad = lane >> 4;

  // staging: thread covers rows r0, r0+16 of the tile, one 16B kchunk each.
  // pre-swizzled global kchunk so linear gload_lds dest realizes the LDS swizzle.
  const int r0 = wid * 32 + (lane >> 2);             // 0..255 (j=0), +16 (j=1)
  const int kc = (lane & 3) ^ ((lane >> 3) & 3);     // slot ^ f(row), f = (row>>1)&3
  const size_t gA0 = (size_t)(m0 + r0) * K_IN + kc * 8;
  const size_t gB0 = (size_t)(n0 + r0) * K_IN + kc * 8;
  const int ldsl = wid * 2048;                       // + j*1024, wave-uniform

  // fragment read offsets (within a section): slot = quad ^ ((row>>1)&3)
  const int su   = quad ^ ((lrow >> 1) & 3);
  const int aoff = ((wm * 128 + lrow) * 4 + su) * 16;
  const int boff = 32768 + ((wn * 64 + lrow) * 4 + su) * 16;

  f4v acc[8][4];
#pragma unroll
  for (int i = 0; i < 8; ++i)
#pragma unroll
    for (int j = 0; j < 4; ++j) acc[i][j] = (f4v){0.f, 0.f, 0.f, 0.f};

#define STAGE_A(NXT, KT, KH)                                                   \
  { const _Float16* g_ = Ah + gA0 + (size_t)(KT) * 64 + (KH) * 32;             \
    char* l_ = smem + (NXT) * 65536 + (KH) * 16384 + ldsl;                     \
    gload16(g_, l_);                                                           \
    gload16(g_ + 16 * K_IN, l_ + 1024); }

#define STAGE_B(NXT, KT, KH)                                                   \
  { const _Float16* g_ = Bh + gB0 + (size_t)(KT) * 64 + (KH) * 32;             \
    char* l_ = smem + (NXT) * 65536 + 32768 + (KH) * 16384 + ldsl;             \
    gload16(g_, l_);                                                           \
    gload16(g_ + 16 * K_IN, l_ + 1024); }

  h8v af[4], bf[4];

// one phase: ds_read subtile, stage one half of a future tile, counted vmcnt,
// barrier, prioritized MFMA cluster, barrier.
#define PHASE(CUR, KS, MH, DO_STAGE, DO_VM)                                    \
  {                                                                            \
    const char* sec_ = smem + (CUR) * 65536 + (KS) * 16384;                    \
    if ((MH) == 0) {                                                           \
      _Pragma("unroll")                                                        \
      for (int nf = 0; nf < 4; ++nf)                                           \
        bf[nf] = *(const h8v*)(sec_ + boff + nf * 1024);                       \
    }                                                                          \
    _Pragma("unroll")                                                          \
    for (int i = 0; i < 4; ++i)                                                \
      af[i] = *(const h8v*)(sec_ + aoff + (MH) * 4096 + i * 1024);             \
    DO_STAGE;                                                                  \
    if (DO_VM) { WAIT_VM4; }                                                   \
    bar();                                                                     \
    __builtin_amdgcn_s_setprio(1);                                             \
    _Pragma("unroll")                                                          \
    for (int mi = 0; mi < 4; ++mi)                                             \
      _Pragma("unroll")                                                        \
      for (int nf = 0; nf < 4; ++nf)                                           \
        acc[(MH) * 4 + mi][nf] = __builtin_amdgcn_mfma_f32_16x16x32_f16(       \
            af[mi], bf[nf], acc[(MH) * 4 + mi][nf], 0, 0, 0);                  \
    __builtin_amdgcn_s_setprio(0);                                             \
    bar();                                                                     \
  }

  // prologue: tile 0 -> buf0 (A0,B0,A1,B1); retire A0,B0; leave A1,B1 in flight
  STAGE_A(0, 0, 0);
  STAGE_B(0, 0, 0);
  STAGE_A(0, 0, 1);
  STAGE_B(0, 0, 1);
  WAIT_VM4;
  bar();

  for (int t = 0; t < 64; t += 2) {
    const int t1 = t + 1;
    const int t2 = (t + 2 < 64) ? t + 2 : 63;  // tail: dummy restage, dead region
    // tile t from buf0, staging tile t+1 -> buf1
    PHASE(0, 0, 0, STAGE_A(1, t1, 0), 0)
    PHASE(0, 0, 1, STAGE_B(1, t1, 0), 1)
    PHASE(0, 1, 0, STAGE_A(1, t1, 1), 0)
    PHASE(0, 1, 1, STAGE_B(1, t1, 1), 1)
    // tile t+1 from buf1, staging tile t+2 -> buf0
    PHASE(1, 0, 0, STAGE_A(0, t2, 0), 0)
    PHASE(1, 0, 1, STAGE_B(0, t2, 0), 1)
    PHASE(1, 1, 0, STAGE_A(0, t2, 1), 0)
    PHASE(1, 1, 1, STAGE_B(0, t2, 1), 1)
  }

  // epilogue: C/D layout col = lane&15 (n), row = quad*4 + reg (m)
#pragma unroll
  for (int mf = 0; mf < 8; ++mf) {
#pragma unroll
    for (int rr = 0; rr < 4; ++rr) {
      int m = m0 + wm * 128 + mf * 16 + quad * 4 + rr;
      float* crow = C + (size_t)m * N_OUT + n0 + wn * 64 + lrow;
#pragma unroll
      for (int nf = 0; nf < 4; ++nf) crow[nf * 16] = acc[mf][nf][rr];
    }
  }
#undef PHASE
#undef STAGE_A
#undef STAGE_B
}

extern "C" void kernel_launch(void* const* d_in, const int* in_sizes, int n_in,
                              void* d_out, int out_size, void* d_ws, size_t ws_size,
                              hipStream_t stream) {
  const float* x   = (const float*)d_in[0];
  const int*   wp  = (const int*)d_in[1];
  const float* wsc = (const float*)d_in[2];
  const int*   wz  = (const int*)d_in[3];

  _Float16* Ah = (_Float16*)d_ws;
  _Float16* Bh = (_Float16*)((char*)d_ws + BH_OFF);

  cvt_x_kernel<<<(M_TOK * (size_t)K_IN) / (8 * 256), 256, 0, stream>>>(x, Ah);
  dequant_w_kernel<<<((size_t)N_OUT * 128) / 256, 256, 0, stream>>>(wp, wsc, wz, Bh);
  gemm_kernel<<<TILES, 512, 0, stream>>>(Ah, Bh, (float*)d_out);
}